// Round 11
// baseline (272.800 us; speedup 1.0000x reference)
//
#include <hip/hip_runtime.h>
#include <math.h>

typedef __bf16 bf16x8 __attribute__((ext_vector_type(8)));
typedef __bf16 bf16x4 __attribute__((ext_vector_type(4)));
typedef float f32x4 __attribute__((ext_vector_type(4)));
typedef float f32x2 __attribute__((ext_vector_type(2)));
typedef unsigned int u32x2 __attribute__((ext_vector_type(2)));
typedef unsigned int u32x4 __attribute__((ext_vector_type(4)));

#define LOG2E 1.4426950408889634f
#define BCAP 8192  // per-bucket region capacity in part[] (expected load ~4340, 60-sigma margin)

// lrelu(e) == max(e, 0.2e) exactly (e>0: e; e<=0: 0.2e) — 2 VALU ops, bitwise-identical result
static __device__ __forceinline__ float lrelu(float e) { return fmaxf(e, 0.2f * e); }
static __device__ __forceinline__ float fexp2(float x) { return __builtin_amdgcn_exp2f(x); }

// permuted-position -> true-channel map: p = blk*64 + l16*4 + ng  <->  c = blk*64 + ng*16 + l16
static __device__ __forceinline__ int cmap(int p) {
  return (p & ~63) + (p & 3) * 16 + ((p & 63) >> 2);
}

// ---------------- prep: weight transposes, layer-2 composite vectors, zero bucket counters ----
__global__ void prep_kernel(const float* __restrict__ W0, __bf16* __restrict__ Bt0,
                            const float* __restrict__ W1, __bf16* __restrict__ Bt1, int FIN,
                            const float* __restrict__ W2, const float* __restrict__ lin_w,
                            const float* __restrict__ a_src2, const float* __restrict__ a_dst2,
                            const float* __restrict__ b2, float* __restrict__ wt,
                            float* __restrict__ vas, float* __restrict__ vad,
                            float* __restrict__ bc, int* __restrict__ cnt, int n) {
  int b = blockIdx.x;
  if (b < 256) {  // Bt0[256][FIN] = W0^T (x unpermuted)
    for (int k = threadIdx.x; k < FIN; k += 256) Bt0[b * FIN + k] = (__bf16)W0[k * 256 + b];
    return;
  }
  b -= 256;
  if (b < 256) {  // Bt1[n][p] = W1[cmap(p)][n]
    int k = threadIdx.x;
    Bt1[b * 256 + k] = (__bf16)W1[cmap(k) * 256 + b];
    return;
  }
  b -= 256;
  if (b == 0) {  // composite layer-2 vectors: one true-channel per thread
    int c = threadIdx.x;
    float qv = 0.f, sv = 0.f, dv = 0.f;
    for (int k = 0; k < 64; k++) {
      float wv = W2[c * 64 + k];
      qv += wv * lin_w[k];
      sv += wv * a_src2[k];
      dv += wv * a_dst2[k];
    }
    wt[c] = qv;
    vas[c] = sv;
    vad[c] = dv;
    if (c == 0) {
      float s = 0.f;
      for (int k = 0; k < 64; k++) s += b2[k] * lin_w[k];
      bc[0] = s;
    }
    return;
  }
  b -= 1;
  // zero bucket counters (re-init every launch: harness re-poisons d_ws)
  int i = b * 256 + threadIdx.x;
  if (i < n) cnt[i] = 0;
}

// ------- FUSED: layer-0 GEMM (f32 A read, in-register bf16 cvt) + bucket-partition --------
template <int K, int NT>
__global__ __launch_bounds__(256) void gemm_part_kernel(
    const float* __restrict__ A, const __bf16* __restrict__ Bt,
    const float* __restrict__ a_src, const float* __restrict__ a_dst,
    unsigned char* __restrict__ C, float* __restrict__ es, float* __restrict__ ed, int M,
    int gmx, const int* __restrict__ srcE, const int* __restrict__ dstE,
    int* __restrict__ bucket_cnt, unsigned int* __restrict__ part, int E, int EE, int n) {
  constexpr int Nc = NT * 64;
  constexpr int H = NT;
  constexpr int KS = K / 32;
  __shared__ __bf16 Bs[2][NT * 64][40];
  if ((int)blockIdx.x >= gmx) {
    int tid = threadIdx.x;
    int* hist = (int*)&Bs[0][0][0];  // 256 ints
    int* gbase = hist + 256;         // 256 ints (2KB total, fits in Bs)
    hist[tid] = 0;
    __syncthreads();
    int ab = ((int)blockIdx.x - gmx) * 4096;
    int sv[16], dv[16];
#pragma unroll
    for (int t = 0; t < 16; t++) {
      int e = ab + t * 256 + tid;
      if (e < EE) {
        if (e < E) { sv[t] = srcE[e]; dv[t] = dstE[e]; }
        else { sv[t] = dv[t] = e - E; }  // self-loops
      } else { sv[t] = -1; dv[t] = 0; }
    }
    int lr[16];
#pragma unroll
    for (int t = 0; t < 16; t++)
      if (sv[t] >= 0) lr[t] = atomicAdd(&hist[dv[t] >> 8], 1);
    __syncthreads();
    int NB = (n + 255) >> 8;
    gbase[tid] = (tid < NB && hist[tid] > 0) ? atomicAdd(&bucket_cnt[tid * 16], hist[tid]) : 0;
    __syncthreads();
#pragma unroll
    for (int t = 0; t < 16; t++)
      if (sv[t] >= 0) {
        int bk = dv[t] >> 8;
        part[(size_t)bk * BCAP + gbase[bk] + lr[t]] =
            (unsigned int)sv[t] | ((unsigned int)(dv[t] & 255) << 24);  // N < 2^24
      }
    return;
  }
  int bid = blockIdx.x;
  int tid = threadIdx.x;
  int wave = tid >> 6;
  int lane = tid & 63;
  int quad = lane >> 4;
  int l16 = lane & 15;
  int rowBase = bid * 64 + wave * 16;
  f32x4 acc[NT * 4] = {};
  int arow = rowBase + l16;
  arow = (arow < M) ? arow : (M - 1);
  const float* Aptr = &A[(size_t)arow * K + quad * 8];
  int sr = tid >> 2;
  int sc = (tid & 3) * 8;
  // prefetch whole per-lane A slice, converting f32 -> bf16 in-register
  bf16x8 af[KS];
#pragma unroll
  for (int s = 0; s < KS; s++) {
    f32x4 lo = *(const f32x4*)&Aptr[s * 32];
    f32x4 hi = *(const f32x4*)&Aptr[s * 32 + 4];
    bf16x8 t;
    t[0] = (__bf16)lo.x; t[1] = (__bf16)lo.y; t[2] = (__bf16)lo.z; t[3] = (__bf16)lo.w;
    t[4] = (__bf16)hi.x; t[5] = (__bf16)hi.y; t[6] = (__bf16)hi.z; t[7] = (__bf16)hi.w;
    af[s] = t;
  }
#pragma unroll
  for (int it = 0; it < NT; it++) {
    int r = it * 64 + sr;
    *(bf16x8*)&Bs[0][r][sc] = *(const bf16x8*)&Bt[(size_t)r * K + sc];
  }
  __syncthreads();
#pragma unroll
  for (int s = 0; s < KS; s++) {
    int cur = s & 1;
    if (s + 1 < KS) {
#pragma unroll
      for (int it = 0; it < NT; it++) {
        int r = it * 64 + sr;
        *(bf16x8*)&Bs[cur ^ 1][r][sc] = *(const bf16x8*)&Bt[(size_t)r * K + (s + 1) * 32 + sc];
      }
    }
#pragma unroll
    for (int ng = 0; ng < NT * 4; ng++) {
      bf16x8 b = *(const bf16x8*)&Bs[cur][ng * 16 + l16][quad * 8];
      acc[ng] = __builtin_amdgcn_mfma_f32_16x16x32_bf16(af[s], b, acc[ng], 0, 0, 0);
    }
    __syncthreads();
  }
  float asv[NT * 4], adv[NT * 4];
#pragma unroll
  for (int ng = 0; ng < NT * 4; ng++) {
    int c = (ng >> 2) * 64 + (ng & 3) * 16 + l16;
    asv[ng] = a_src[c];
    adv[ng] = a_dst[c];
  }
#pragma unroll
  for (int r = 0; r < 4; r++) {
    int row = rowBase + quad * 4 + r;
#pragma unroll
    for (int h = 0; h < H; h++) {
      float ss = 0.f, sd = 0.f;
#pragma unroll
      for (int g = 0; g < 4; g++) {
        float hv = acc[h * 4 + g][r];
        ss += hv * asv[h * 4 + g];
        sd += hv * adv[h * 4 + g];
      }
#pragma unroll
      for (int o = 1; o < 16; o <<= 1) {
        ss += __shfl_xor(ss, o);
        sd += __shfl_xor(sd, o);
      }
      if (row < M) {
        if (l16 == 0) {
          es[row * H + h] = ss * LOG2E;  // pre-scaled for exp2 in aggregate
          ed[row * H + h] = sd * LOG2E;
        }
        unsigned int pk = 0;
        pk = __builtin_amdgcn_cvt_pk_fp8_f32(acc[h * 4 + 0][r], acc[h * 4 + 1][r], pk, false);
        pk = __builtin_amdgcn_cvt_pk_fp8_f32(acc[h * 4 + 2][r], acc[h * 4 + 3][r], pk, true);
        *(unsigned int*)&C[(size_t)row * Nc + h * 64 + l16 * 4] = pk;
      }
    }
  }
}

// ------- per-bucket CSR finalize: one block per 256-node bucket, all ranks in LDS --------
__global__ __launch_bounds__(1024) void bucket_csr_kernel(
    const unsigned int* __restrict__ part, const int* __restrict__ bucket_cnt,
    int* __restrict__ offsets, int* __restrict__ src_sorted, int n, int EE) {
  __shared__ int sc[256];
  __shared__ int excl[256];
  __shared__ int run[256];
  int tid = threadIdx.x;
  int b = blockIdx.x;
  int NB = (n + 255) >> 8;
  if (tid < 256) sc[tid] = (tid < NB) ? bucket_cnt[tid * 16] : 0;
  __syncthreads();
  for (int d = 1; d < 256; d <<= 1) {
    int t = 0;
    if (tid < 256 && tid >= d) t = sc[tid - d];
    __syncthreads();
    if (tid < 256) sc[tid] += t;
    __syncthreads();
  }
  int base = (b == 0) ? 0 : sc[b - 1];
  int cb = sc[b] - base;
  const unsigned int* mypart = part + (size_t)b * BCAP;
  if (tid < 256) run[tid] = 0;
  __syncthreads();
  for (int i = tid; i < cb; i += 1024) atomicAdd(&run[mypart[i] >> 24], 1);
  __syncthreads();
  int myc = (tid < 256) ? run[tid] : 0;
  if (tid < 256) sc[tid] = myc;
  __syncthreads();
  for (int d = 1; d < 256; d <<= 1) {
    int t = 0;
    if (tid < 256 && tid >= d) t = sc[tid - d];
    __syncthreads();
    if (tid < 256) sc[tid] += t;
    __syncthreads();
  }
  if (tid < 256) {
    excl[tid] = sc[tid] - myc;
    int node = b * 256 + tid;
    if (node < n) offsets[node] = base + excl[tid];
    run[tid] = 0;
  }
  if (b == 0 && tid == 0) offsets[n] = EE;
  __syncthreads();
  for (int i = tid; i < cb; i += 1024) {
    unsigned int p = mypart[i];
    int j = p >> 24;
    int r = atomicAdd(&run[j], 1);
    src_sorted[base + excl[j] + r] = (int)(p & 0xFFFFFFu);
  }
}

// plain single-pass GEMM (layer 1): 64-row tile, full-A prefetch + dbuf Bs
template <int K, int NT>
__global__ __launch_bounds__(256) void gemm2_kernel(const __bf16* __restrict__ A,
                                                    const __bf16* __restrict__ Bt,
                                                    const float* __restrict__ a_src,
                                                    const float* __restrict__ a_dst,
                                                    unsigned char* __restrict__ C,
                                                    float* __restrict__ es,
                                                    float* __restrict__ ed, int M) {
  constexpr int Nc = NT * 64;
  constexpr int H = NT;
  constexpr int KS = K / 32;
  __shared__ __bf16 Bs[2][NT * 64][40];
  int tid = threadIdx.x;
  int wave = tid >> 6;
  int lane = tid & 63;
  int quad = lane >> 4;
  int l16 = lane & 15;
  int rowBase = blockIdx.x * 64 + wave * 16;
  f32x4 acc[NT * 4] = {};
  int arow = rowBase + l16;
  arow = (arow < M) ? arow : (M - 1);
  const __bf16* Aptr = &A[(size_t)arow * K + quad * 8];
  int sr = tid >> 2;
  int sc = (tid & 3) * 8;
  bf16x8 af[KS];
#pragma unroll
  for (int s = 0; s < KS; s++) af[s] = *(const bf16x8*)&Aptr[s * 32];
#pragma unroll
  for (int it = 0; it < NT; it++) {
    int r = it * 64 + sr;
    *(bf16x8*)&Bs[0][r][sc] = *(const bf16x8*)&Bt[(size_t)r * K + sc];
  }
  __syncthreads();
#pragma unroll
  for (int s = 0; s < KS; s++) {
    int cur = s & 1;
    if (s + 1 < KS) {
#pragma unroll
      for (int it = 0; it < NT; it++) {
        int r = it * 64 + sr;
        *(bf16x8*)&Bs[cur ^ 1][r][sc] = *(const bf16x8*)&Bt[(size_t)r * K + (s + 1) * 32 + sc];
      }
    }
#pragma unroll
    for (int ng = 0; ng < NT * 4; ng++) {
      bf16x8 b = *(const bf16x8*)&Bs[cur][ng * 16 + l16][quad * 8];
      acc[ng] = __builtin_amdgcn_mfma_f32_16x16x32_bf16(af[s], b, acc[ng], 0, 0, 0);
    }
    __syncthreads();
  }
  float asv[NT * 4], adv[NT * 4];
#pragma unroll
  for (int ng = 0; ng < NT * 4; ng++) {
    int c = (ng >> 2) * 64 + (ng & 3) * 16 + l16;
    asv[ng] = a_src[c];
    adv[ng] = a_dst[c];
  }
#pragma unroll
  for (int r = 0; r < 4; r++) {
    int row = rowBase + quad * 4 + r;
#pragma unroll
    for (int h = 0; h < H; h++) {
      float ss = 0.f, sd = 0.f;
#pragma unroll
      for (int g = 0; g < 4; g++) {
        float hv = acc[h * 4 + g][r];
        ss += hv * asv[h * 4 + g];
        sd += hv * adv[h * 4 + g];
      }
#pragma unroll
      for (int o = 1; o < 16; o <<= 1) {
        ss += __shfl_xor(ss, o);
        sd += __shfl_xor(sd, o);
      }
      if (row < M) {
        if (l16 == 0) {
          es[row * H + h] = ss * LOG2E;
          ed[row * H + h] = sd * LOG2E;
        }
        unsigned int pk = 0;
        pk = __builtin_amdgcn_cvt_pk_fp8_f32(acc[h * 4 + 0][r], acc[h * 4 + 1][r], pk, false);
        pk = __builtin_amdgcn_cvt_pk_fp8_f32(acc[h * 4 + 2][r], acc[h * 4 + 3][r], pk, true);
        *(unsigned int*)&C[(size_t)row * Nc + h * 64 + l16 * 4] = pk;
      }
    }
  }
}

// ======= aggregation, group-per-node layout: 1 node per 16-lane group (4 nodes/wave). =======
// Each lane owns 16 channels of ITS node -> acc[16] covers disjoint channels: NO cross-lane
// channel reduce, NO sw reduce (all 16 lanes compute identical scalars). Epilogue instructions
// serve 4 nodes per wave. Index list (32 deep) in registers; pair-pipelined gathers; tail for
// deg>32 via broadcast loads.

// shared edge-accumulate: decode 16 fp8 channels, FMA with weight w
static __device__ __forceinline__ void accum16(const u32x4& u, float w, float* acc) {
#pragma unroll
  for (int i = 0; i < 4; i++) {
    f32x2 a = __builtin_amdgcn_cvt_pk_f32_fp8(u[i], false);
    f32x2 b = __builtin_amdgcn_cvt_pk_f32_fp8(u[i], true);
    acc[i * 4 + 0] += w * a.x;
    acc[i * 4 + 1] += w * a.y;
    acc[i * 4 + 2] += w * b.x;
    acc[i * 4 + 3] += w * b.y;
  }
}

// ------- layer-0 aggregate: writes bf16 hB row -------
__global__ void agg256_kernel(const unsigned char* __restrict__ h, const int* __restrict__ offsets,
                              const int* __restrict__ src_sorted, const float* __restrict__ es,
                              const float* __restrict__ ed, const float* __restrict__ bias,
                              __bf16* __restrict__ out, int n) {
  int tid = threadIdx.x;
  int node = blockIdx.x * 16 + (tid >> 4);
  if (node >= n) return;
  int g16 = tid & 15;
  int lbase = (tid & 63) & 48;  // group base lane within wave
  unsigned hd = (unsigned)(g16 >> 2);
  unsigned cOff = (unsigned)(g16 * 16);
  float myEd = ed[node * 4 + hd];
  int off = offsets[node];
  int deg = offsets[node + 1] - off;
  int idx0 = (g16 < deg) ? src_sorted[off + g16] : 0;
  int idx1 = (16 + g16 < deg) ? src_sorted[off + 16 + g16] : 0;
  int nmain = deg < 32 ? deg : 32;
  float acc[16] = {};
  float sw = 0.f;
  int e = 0;
  float eA0 = 0.f, eA1 = 0.f;
  u32x4 uA0 = {}, uA1 = {};
  if (e < nmain) {
    unsigned s = (unsigned)__shfl(e < 16 ? idx0 : idx1, lbase | (e & 15));
    eA0 = es[s * 4u + hd];
    uA0 = *(const u32x4*)(h + (s << 8) + cOff);
  }
  if (e + 1 < nmain) {
    unsigned s = (unsigned)__shfl(e + 1 < 16 ? idx0 : idx1, lbase | ((e + 1) & 15));
    eA1 = es[s * 4u + hd];
    uA1 = *(const u32x4*)(h + (s << 8) + cOff);
  }
  while (e < nmain) {
    int en = e + 2;
    float eB0 = 0.f, eB1 = 0.f;
    u32x4 uB0 = {}, uB1 = {};
    if (en < nmain) {  // prefetch next pair before consuming current
      unsigned s = (unsigned)__shfl(en < 16 ? idx0 : idx1, lbase | (en & 15));
      eB0 = es[s * 4u + hd];
      uB0 = *(const u32x4*)(h + (s << 8) + cOff);
    }
    if (en + 1 < nmain) {
      unsigned s = (unsigned)__shfl(en + 1 < 16 ? idx0 : idx1, lbase | ((en + 1) & 15));
      eB1 = es[s * 4u + hd];
      uB1 = *(const u32x4*)(h + (s << 8) + cOff);
    }
    float w0 = fexp2(lrelu(eA0 + myEd));
    float w1 = (e + 1 < nmain) ? fexp2(lrelu(eA1 + myEd)) : 0.f;
    sw += w0 + w1;
    accum16(uA0, w0, acc);
    accum16(uA1, w1, acc);  // w1=0 and uA1={} when invalid -> adds 0
    eA0 = eB0; eA1 = eB1; uA0 = uB0; uA1 = uB1;
    e = en;
  }
  for (int t = 32; t < deg; t++) {  // rare deg>32 tail: broadcast index
    unsigned s = (unsigned)src_sorted[off + t];
    float w = fexp2(lrelu(es[s * 4u + hd] + myEd));
    sw += w;
    u32x4 u = *(const u32x4*)(h + (s << 8) + cOff);
    accum16(u, w, acc);
  }
  float invS = 1.0f / (sw + 1e-16f);
  bf16x8 o0, o1;
#pragma unroll
  for (int k = 0; k < 16; k++) {
    int c = (int)hd * 64 + (k & 3) * 16 + (g16 & 3) * 4 + (k >> 2);  // cmap(g16*16+k)
    float v = fmaxf(acc[k] * invS + bias[c], 0.f);
    if (k < 8) o0[k] = (__bf16)v; else o1[k - 8] = (__bf16)v;
  }
  *(bf16x8*)&out[(size_t)node * 256 + g16 * 16] = o0;
  *(bf16x8*)&out[(size_t)node * 256 + g16 * 16 + 8] = o1;
}

// ------- layer-1 aggregate with FUSED layer-2 projections (group-per-node layout) -------
__global__ void agg256f_kernel(const unsigned char* __restrict__ h, const int* __restrict__ offsets,
                               const int* __restrict__ src_sorted, const float* __restrict__ es,
                               const float* __restrict__ ed, const float* __restrict__ bias,
                               const float* __restrict__ wt, const float* __restrict__ vas,
                               const float* __restrict__ vad, f32x2* __restrict__ qes,
                               float* __restrict__ ed2, int n) {
  int tid = threadIdx.x;
  int node = blockIdx.x * 16 + (tid >> 4);
  if (node >= n) return;
  int g16 = tid & 15;
  int lbase = (tid & 63) & 48;
  unsigned hd = (unsigned)(g16 >> 2);
  unsigned cOff = (unsigned)(g16 * 16);
  float myEd = ed[node * 4 + hd];
  int off = offsets[node];
  int deg = offsets[node + 1] - off;
  int idx0 = (g16 < deg) ? src_sorted[off + g16] : 0;
  int idx1 = (16 + g16 < deg) ? src_sorted[off + 16 + g16] : 0;
  int nmain = deg < 32 ? deg : 32;
  float acc[16] = {};
  float sw = 0.f;
  int e = 0;
  float eA0 = 0.f, eA1 = 0.f;
  u32x4 uA0 = {}, uA1 = {};
  if (e < nmain) {
    unsigned s = (unsigned)__shfl(e < 16 ? idx0 : idx1, lbase | (e & 15));
    eA0 = es[s * 4u + hd];
    uA0 = *(const u32x4*)(h + (s << 8) + cOff);
  }
  if (e + 1 < nmain) {
    unsigned s = (unsigned)__shfl(e + 1 < 16 ? idx0 : idx1, lbase | ((e + 1) & 15));
    eA1 = es[s * 4u + hd];
    uA1 = *(const u32x4*)(h + (s << 8) + cOff);
  }
  while (e < nmain) {
    int en = e + 2;
    float eB0 = 0.f, eB1 = 0.f;
    u32x4 uB0 = {}, uB1 = {};
    if (en < nmain) {
      unsigned s = (unsigned)__shfl(en < 16 ? idx0 : idx1, lbase | (en & 15));
      eB0 = es[s * 4u + hd];
      uB0 = *(const u32x4*)(h + (s << 8) + cOff);
    }
    if (en + 1 < nmain) {
      unsigned s = (unsigned)__shfl(en + 1 < 16 ? idx0 : idx1, lbase | ((en + 1) & 15));
      eB1 = es[s * 4u + hd];
      uB1 = *(const u32x4*)(h + (s << 8) + cOff);
    }
    float w0 = fexp2(lrelu(eA0 + myEd));
    float w1 = (e + 1 < nmain) ? fexp2(lrelu(eA1 + myEd)) : 0.f;
    sw += w0 + w1;
    accum16(uA0, w0, acc);
    accum16(uA1, w1, acc);
    eA0 = eB0; eA1 = eB1; uA0 = uB0; uA1 = uB1;
    e = en;
  }
  for (int t = 32; t < deg; t++) {
    unsigned s = (unsigned)src_sorted[off + t];
    float w = fexp2(lrelu(es[s * 4u + hd] + myEd));
    sw += w;
    u32x4 u = *(const u32x4*)(h + (s << 8) + cOff);
    accum16(u, w, acc);
  }
  float invS = 1.0f / (sw + 1e-16f);
  // fused layer-2 projections: lane g16 owns 16 true channels; partial dots + 16-lane reduce
  float q = 0.f, s2 = 0.f, d2 = 0.f;
#pragma unroll
  for (int k = 0; k < 16; k++) {
    int c = (int)hd * 64 + (k & 3) * 16 + (g16 & 3) * 4 + (k >> 2);  // cmap(g16*16+k)
    float v = fmaxf(acc[k] * invS + bias[c], 0.f);
    q += v * wt[c];
    s2 += v * vas[c];
    d2 += v * vad[c];
  }
#pragma unroll
  for (int o = 1; o < 16; o <<= 1) {
    q += __shfl_xor(q, o);
    s2 += __shfl_xor(s2, o);
    d2 += __shfl_xor(d2, o);
  }
  if (g16 == 0) {
    f32x2 r;
    r.x = q;
    r.y = s2 * LOG2E;  // pre-scaled for exp2
    qes[node] = r;
    ed2[node] = d2 * LOG2E;
  }
}

// ------- layer-2 aggregate + final linear on scalars (400KB L2-resident table) -------
__global__ void agg64v2_kernel(const f32x2* __restrict__ qes, const float* __restrict__ ed2,
                               const int* __restrict__ offsets, const int* __restrict__ src_sorted,
                               const float* __restrict__ bc, float* __restrict__ pnode, int n) {
  int node = blockIdx.x * (blockDim.x >> 6) + (threadIdx.x >> 6);
  int lane = threadIdx.x & 63;
  if (node >= n) return;
  float myEd = ed2[node];
  int off = offsets[node];
  int deg = offsets[node + 1] - off;
  float sw = 0.f, swq = 0.f;
  for (int j = lane; j < deg; j += 64) {
    int s = src_sorted[off + j];
    f32x2 v = qes[s];
    float w = fexp2(lrelu(v.y + myEd));
    sw += w;
    swq += w * v.x;
  }
#pragma unroll
  for (int o = 1; o < 64; o <<= 1) {
    sw += __shfl_xor(sw, o);
    swq += __shfl_xor(swq, o);
  }
  if (lane == 0) pnode[node] = swq / (sw + 1e-16f) + bc[0];
}

// ---------------- FUSED pool+final: block g binary-searches its segment, reduces, writes out ----
static __device__ __forceinline__ int lowerb(const int* __restrict__ a, int n, int key) {
  int lo = 0, hi = n;
  while (lo < hi) {
    int mid = (lo + hi) >> 1;
    if (a[mid] < key) lo = mid + 1; else hi = mid;
  }
  return lo;
}

__global__ void poolfinal_kernel(const float* __restrict__ pnode, const int* __restrict__ batch,
                                 const float* __restrict__ lin_b, float* __restrict__ out, int n) {
  __shared__ float ws[4];
  int g = blockIdx.x;
  int start = lowerb(batch, n, g);
  int end = lowerb(batch, n, g + 1);
  float acc = 0.f;
  for (int i = start + threadIdx.x; i < end; i += 256) acc += pnode[i];
  for (int o = 32; o > 0; o >>= 1) acc += __shfl_down(acc, o);
  if ((threadIdx.x & 63) == 0) ws[threadIdx.x >> 6] = acc;
  __syncthreads();
  if (threadIdx.x == 0) {
    float total = ws[0] + ws[1] + ws[2] + ws[3];
    out[g] = total / fmaxf((float)(end - start), 1.0f) + lin_b[0];
  }
}

extern "C" void kernel_launch(void* const* d_in, const int* in_sizes, int n_in, void* d_out,
                              int out_size, void* d_ws, size_t ws_size, hipStream_t stream) {
  const float* x = (const float*)d_in[0];
  const int* edge_index = (const int*)d_in[1];
  const int* batch = (const int*)d_in[2];
  const float* W0 = (const float*)d_in[3];
  const float* a_src0 = (const float*)d_in[4];
  const float* a_dst0 = (const float*)d_in[5];
  const float* b0 = (const float*)d_in[6];
  const float* W1 = (const float*)d_in[7];
  const float* a_src1 = (const float*)d_in[8];
  const float* a_dst1 = (const float*)d_in[9];
  const float* b1 = (const float*)d_in[10];
  const float* W2 = (const float*)d_in[11];
  const float* a_src2 = (const float*)d_in[12];
  const float* a_dst2 = (const float*)d_in[13];
  const float* b2 = (const float*)d_in[14];
  const float* lin_w = (const float*)d_in[15];
  const float* lin_b = (const float*)d_in[16];
  float* out = (float*)d_out;

  const int N = in_sizes[2];      // 50000
  const int E = in_sizes[1] / 2;  // 800000
  const int EE = E + N;
  const int G = 64;
  const int FIN = in_sizes[0] / N;  // 128

  const int* srcArr = edge_index;
  const int* dstArr = edge_index + E;

  // workspace carve (256B aligned)
  size_t off = 0;
  auto alloc = [&](size_t bytes) -> void* {
    off = (off + 255) & ~(size_t)255;
    void* p = (char*)d_ws + off;
    off += bytes;
    return p;
  };
  unsigned char* hA = (unsigned char*)alloc((size_t)N * 256);  // GEMM out, fp8 permuted
  __bf16* hB = (__bf16*)alloc((size_t)N * 256 * 2);            // layer-0 aggregate out, bf16
  float* pnode = (float*)alloc((size_t)N * 4);
  __bf16* Bt0 = (__bf16*)alloc((size_t)256 * FIN * 2);
  __bf16* Bt1 = (__bf16*)alloc((size_t)256 * 256 * 2);
  float* es = (float*)alloc((size_t)N * 4 * 4);
  float* ed = (float*)alloc((size_t)N * 4 * 4);
  int* offsets = (int*)alloc((size_t)(N + 1) * 4);
  int* src_sorted = (int*)alloc((size_t)EE * 4);
  int* bucket_cnt = (int*)alloc((size_t)4096 * 4);  // 196 buckets padded to 64B stride
  f32x2* qes = (f32x2*)alloc((size_t)N * 8);        // {q_j, es2_j} packed for one 8B gather
  float* ed2 = (float*)alloc((size_t)N * 4);
  float* wt = (float*)alloc(256 * 4);
  float* vas = (float*)alloc(256 * 4);
  float* vad = (float*)alloc(256 * 4);
  float* bc = (float*)alloc(256);  // 1 float, padded
  (void)ws_size;

  int NB = (N + 255) >> 8;  // dst-range buckets (256 nodes each)

  // part[] lives only between gemm_part and bucket_csr; hB is first written later by
  // agg256 -> alias part onto hB (NB*BCAP*4 = 6.4MB << 25.6MB).
  unsigned int* part = (unsigned int*)hB;

  int nwb = (N + 3) / 4;        // agg64v2: one node per wave, 4 waves/block
  int ngb = (N + 15) / 16;      // agg256*: one node per 16-lane group, 16 nodes/block
  int gmx = (N + 63) / 64;      // GEMM M-blocks (64 rows each)
  int nA = (EE + 4095) / 4096;  // partition blocks (4096 edges each)

  // ---- prep (weight transposes + layer-2 composite vectors + zero bucket counters) ----
  prep_kernel<<<256 + 256 + 1 + 16, 256, 0, stream>>>(W0, Bt0, W1, Bt1, FIN, W2, lin_w, a_src2,
                                                      a_dst2, b2, wt, vas, vad, bc, bucket_cnt,
                                                      4096);

  // ---- layer-0 GEMM (reads f32 x directly, cvt in-register) + edge bucket-partition ----
  gemm_part_kernel<128, 4><<<gmx + nA, 256, 0, stream>>>(
      x, Bt0, a_src0, a_dst0, hA, es, ed, N, gmx, srcArr, dstArr, bucket_cnt, part, E, EE, N);

  // ---- per-bucket CSR finalize ----
  bucket_csr_kernel<<<NB, 1024, 0, stream>>>(part, bucket_cnt, offsets, src_sorted, N, EE);

  // ---- layer 0 aggregate (group-per-node) ----
  agg256_kernel<<<ngb, 256, 0, stream>>>(hA, offsets, src_sorted, es, ed, b0, hB, N);

  // ---- layer 1: 256 -> 4x64 concat, relu ----
  gemm2_kernel<256, 4><<<gmx, 256, 0, stream>>>(hB, Bt1, a_src1, a_dst1, hA, es, ed, N);

  // ---- layer-1 aggregate with fused layer-2 projections (group-per-node) ----
  agg256f_kernel<<<ngb, 256, 0, stream>>>(hA, offsets, src_sorted, es, ed, b1, wt, vas, vad, qes,
                                          ed2, N);

  // ---- layer-2 aggregate + final linear on scalars (L2-resident 400KB gather table) ----
  agg64v2_kernel<<<nwb, 256, 0, stream>>>(qes, ed2, offsets, src_sorted, bc, pnode, N);

  // ---- fused global mean pool + bias (binary-search segments) ----
  poolfinal_kernel<<<G, 256, 0, stream>>>(pnode, batch, lin_b, out, N);
}

// Round 13
// 256.340 us; speedup vs baseline: 1.0642x; 1.0642x over previous
//
#include <hip/hip_runtime.h>
#include <math.h>

typedef __bf16 bf16x8 __attribute__((ext_vector_type(8)));
typedef __bf16 bf16x4 __attribute__((ext_vector_type(4)));
typedef float f32x4 __attribute__((ext_vector_type(4)));
typedef float f32x2 __attribute__((ext_vector_type(2)));
typedef unsigned int u32x2 __attribute__((ext_vector_type(2)));
typedef unsigned int u32x4 __attribute__((ext_vector_type(4)));

#define LOG2E 1.4426950408889634f
#define BCAP 8192  // per-bucket region capacity in part[] (expected load ~4340, 60-sigma margin)

// lrelu(e) == max(e, 0.2e) exactly (e>0: e; e<=0: 0.2e) — 2 VALU ops, bitwise-identical result
static __device__ __forceinline__ float lrelu(float e) { return fmaxf(e, 0.2f * e); }
static __device__ __forceinline__ float fexp2(float x) { return __builtin_amdgcn_exp2f(x); }

// permuted-position -> true-channel map: p = blk*64 + l16*4 + ng  <->  c = blk*64 + ng*16 + l16
static __device__ __forceinline__ int cmap(int p) {
  return (p & ~63) + (p & 3) * 16 + ((p & 63) >> 2);
}

// ---------------- prep: weight transposes, layer-2 composite vectors, zero bucket counters ----
__global__ void prep_kernel(const float* __restrict__ W0, __bf16* __restrict__ Bt0,
                            const float* __restrict__ W1, __bf16* __restrict__ Bt1, int FIN,
                            const float* __restrict__ W2, const float* __restrict__ lin_w,
                            const float* __restrict__ a_src2, const float* __restrict__ a_dst2,
                            const float* __restrict__ b2, float* __restrict__ wt,
                            float* __restrict__ vas, float* __restrict__ vad,
                            float* __restrict__ bc, int* __restrict__ cnt, int n) {
  int b = blockIdx.x;
  if (b < 256) {  // Bt0[256][FIN] = W0^T (x unpermuted)
    for (int k = threadIdx.x; k < FIN; k += 256) Bt0[b * FIN + k] = (__bf16)W0[k * 256 + b];
    return;
  }
  b -= 256;
  if (b < 256) {  // Bt1[n][p] = W1[cmap(p)][n]
    int k = threadIdx.x;
    Bt1[b * 256 + k] = (__bf16)W1[cmap(k) * 256 + b];
    return;
  }
  b -= 256;
  if (b == 0) {  // composite layer-2 vectors: one true-channel per thread
    int c = threadIdx.x;
    float qv = 0.f, sv = 0.f, dv = 0.f;
    for (int k = 0; k < 64; k++) {
      float wv = W2[c * 64 + k];
      qv += wv * lin_w[k];
      sv += wv * a_src2[k];
      dv += wv * a_dst2[k];
    }
    wt[c] = qv;
    vas[c] = sv;
    vad[c] = dv;
    if (c == 0) {
      float s = 0.f;
      for (int k = 0; k < 64; k++) s += b2[k] * lin_w[k];
      bc[0] = s;
    }
    return;
  }
  b -= 1;
  // zero bucket counters (re-init every launch: harness re-poisons d_ws)
  int i = b * 256 + threadIdx.x;
  if (i < n) cnt[i] = 0;
}

// ------- FUSED: layer-0 GEMM (f32 A read, in-register bf16 cvt) + bucket-partition --------
template <int K, int NT>
__global__ __launch_bounds__(256) void gemm_part_kernel(
    const float* __restrict__ A, const __bf16* __restrict__ Bt,
    const float* __restrict__ a_src, const float* __restrict__ a_dst,
    unsigned char* __restrict__ C, float* __restrict__ es, float* __restrict__ ed, int M,
    int gmx, const int* __restrict__ srcE, const int* __restrict__ dstE,
    int* __restrict__ bucket_cnt, unsigned int* __restrict__ part, int E, int EE, int n) {
  constexpr int Nc = NT * 64;
  constexpr int H = NT;
  constexpr int KS = K / 32;
  __shared__ __bf16 Bs[2][NT * 64][40];
  if ((int)blockIdx.x >= gmx) {
    int tid = threadIdx.x;
    int* hist = (int*)&Bs[0][0][0];  // 256 ints
    int* gbase = hist + 256;         // 256 ints (2KB total, fits in Bs)
    hist[tid] = 0;
    __syncthreads();
    int ab = ((int)blockIdx.x - gmx) * 4096;
    int sv[16], dv[16];
#pragma unroll
    for (int t = 0; t < 16; t++) {
      int e = ab + t * 256 + tid;
      if (e < EE) {
        if (e < E) { sv[t] = srcE[e]; dv[t] = dstE[e]; }
        else { sv[t] = dv[t] = e - E; }  // self-loops
      } else { sv[t] = -1; dv[t] = 0; }
    }
    int lr[16];
#pragma unroll
    for (int t = 0; t < 16; t++)
      if (sv[t] >= 0) lr[t] = atomicAdd(&hist[dv[t] >> 8], 1);
    __syncthreads();
    int NB = (n + 255) >> 8;
    gbase[tid] = (tid < NB && hist[tid] > 0) ? atomicAdd(&bucket_cnt[tid * 16], hist[tid]) : 0;
    __syncthreads();
#pragma unroll
    for (int t = 0; t < 16; t++)
      if (sv[t] >= 0) {
        int bk = dv[t] >> 8;
        part[(size_t)bk * BCAP + gbase[bk] + lr[t]] =
            (unsigned int)sv[t] | ((unsigned int)(dv[t] & 255) << 24);  // N < 2^24
      }
    return;
  }
  int bid = blockIdx.x;
  int tid = threadIdx.x;
  int wave = tid >> 6;
  int lane = tid & 63;
  int quad = lane >> 4;
  int l16 = lane & 15;
  int rowBase = bid * 64 + wave * 16;
  f32x4 acc[NT * 4] = {};
  int arow = rowBase + l16;
  arow = (arow < M) ? arow : (M - 1);
  const float* Aptr = &A[(size_t)arow * K + quad * 8];
  int sr = tid >> 2;
  int sc = (tid & 3) * 8;
  // prefetch whole per-lane A slice, converting f32 -> bf16 in-register
  bf16x8 af[KS];
#pragma unroll
  for (int s = 0; s < KS; s++) {
    f32x4 lo = *(const f32x4*)&Aptr[s * 32];
    f32x4 hi = *(const f32x4*)&Aptr[s * 32 + 4];
    bf16x8 t;
    t[0] = (__bf16)lo.x; t[1] = (__bf16)lo.y; t[2] = (__bf16)lo.z; t[3] = (__bf16)lo.w;
    t[4] = (__bf16)hi.x; t[5] = (__bf16)hi.y; t[6] = (__bf16)hi.z; t[7] = (__bf16)hi.w;
    af[s] = t;
  }
#pragma unroll
  for (int it = 0; it < NT; it++) {
    int r = it * 64 + sr;
    *(bf16x8*)&Bs[0][r][sc] = *(const bf16x8*)&Bt[(size_t)r * K + sc];
  }
  __syncthreads();
#pragma unroll
  for (int s = 0; s < KS; s++) {
    int cur = s & 1;
    if (s + 1 < KS) {
#pragma unroll
      for (int it = 0; it < NT; it++) {
        int r = it * 64 + sr;
        *(bf16x8*)&Bs[cur ^ 1][r][sc] = *(const bf16x8*)&Bt[(size_t)r * K + (s + 1) * 32 + sc];
      }
    }
#pragma unroll
    for (int ng = 0; ng < NT * 4; ng++) {
      bf16x8 b = *(const bf16x8*)&Bs[cur][ng * 16 + l16][quad * 8];
      acc[ng] = __builtin_amdgcn_mfma_f32_16x16x32_bf16(af[s], b, acc[ng], 0, 0, 0);
    }
    __syncthreads();
  }
  float asv[NT * 4], adv[NT * 4];
#pragma unroll
  for (int ng = 0; ng < NT * 4; ng++) {
    int c = (ng >> 2) * 64 + (ng & 3) * 16 + l16;
    asv[ng] = a_src[c];
    adv[ng] = a_dst[c];
  }
#pragma unroll
  for (int r = 0; r < 4; r++) {
    int row = rowBase + quad * 4 + r;
#pragma unroll
    for (int h = 0; h < H; h++) {
      float ss = 0.f, sd = 0.f;
#pragma unroll
      for (int g = 0; g < 4; g++) {
        float hv = acc[h * 4 + g][r];
        ss += hv * asv[h * 4 + g];
        sd += hv * adv[h * 4 + g];
      }
#pragma unroll
      for (int o = 1; o < 16; o <<= 1) {
        ss += __shfl_xor(ss, o);
        sd += __shfl_xor(sd, o);
      }
      if (row < M) {
        if (l16 == 0) {
          es[row * H + h] = ss * LOG2E;  // pre-scaled for exp2 in aggregate
          ed[row * H + h] = sd * LOG2E;
        }
        unsigned int pk = 0;
        pk = __builtin_amdgcn_cvt_pk_fp8_f32(acc[h * 4 + 0][r], acc[h * 4 + 1][r], pk, false);
        pk = __builtin_amdgcn_cvt_pk_fp8_f32(acc[h * 4 + 2][r], acc[h * 4 + 3][r], pk, true);
        *(unsigned int*)&C[(size_t)row * Nc + h * 64 + l16 * 4] = pk;
      }
    }
  }
}

// ------- per-bucket CSR finalize: one block per 256-node bucket, all ranks in LDS --------
__global__ __launch_bounds__(1024) void bucket_csr_kernel(
    const unsigned int* __restrict__ part, const int* __restrict__ bucket_cnt,
    int* __restrict__ offsets, int* __restrict__ src_sorted, int n, int EE) {
  __shared__ int sc[256];
  __shared__ int excl[256];
  __shared__ int run[256];
  int tid = threadIdx.x;
  int b = blockIdx.x;
  int NB = (n + 255) >> 8;
  if (tid < 256) sc[tid] = (tid < NB) ? bucket_cnt[tid * 16] : 0;
  __syncthreads();
  for (int d = 1; d < 256; d <<= 1) {
    int t = 0;
    if (tid < 256 && tid >= d) t = sc[tid - d];
    __syncthreads();
    if (tid < 256) sc[tid] += t;
    __syncthreads();
  }
  int base = (b == 0) ? 0 : sc[b - 1];
  int cb = sc[b] - base;
  const unsigned int* mypart = part + (size_t)b * BCAP;
  if (tid < 256) run[tid] = 0;
  __syncthreads();
  for (int i = tid; i < cb; i += 1024) atomicAdd(&run[mypart[i] >> 24], 1);
  __syncthreads();
  int myc = (tid < 256) ? run[tid] : 0;
  if (tid < 256) sc[tid] = myc;
  __syncthreads();
  for (int d = 1; d < 256; d <<= 1) {
    int t = 0;
    if (tid < 256 && tid >= d) t = sc[tid - d];
    __syncthreads();
    if (tid < 256) sc[tid] += t;
    __syncthreads();
  }
  if (tid < 256) {
    excl[tid] = sc[tid] - myc;
    int node = b * 256 + tid;
    if (node < n) offsets[node] = base + excl[tid];
    run[tid] = 0;
  }
  if (b == 0 && tid == 0) offsets[n] = EE;
  __syncthreads();
  for (int i = tid; i < cb; i += 1024) {
    unsigned int p = mypart[i];
    int j = p >> 24;
    int r = atomicAdd(&run[j], 1);
    src_sorted[base + excl[j] + r] = (int)(p & 0xFFFFFFu);
  }
}

// plain single-pass GEMM (layer 1): 64-row tile, full-A prefetch + dbuf Bs
template <int K, int NT>
__global__ __launch_bounds__(256) void gemm2_kernel(const __bf16* __restrict__ A,
                                                    const __bf16* __restrict__ Bt,
                                                    const float* __restrict__ a_src,
                                                    const float* __restrict__ a_dst,
                                                    unsigned char* __restrict__ C,
                                                    float* __restrict__ es,
                                                    float* __restrict__ ed, int M) {
  constexpr int Nc = NT * 64;
  constexpr int H = NT;
  constexpr int KS = K / 32;
  __shared__ __bf16 Bs[2][NT * 64][40];
  int tid = threadIdx.x;
  int wave = tid >> 6;
  int lane = tid & 63;
  int quad = lane >> 4;
  int l16 = lane & 15;
  int rowBase = blockIdx.x * 64 + wave * 16;
  f32x4 acc[NT * 4] = {};
  int arow = rowBase + l16;
  arow = (arow < M) ? arow : (M - 1);
  const __bf16* Aptr = &A[(size_t)arow * K + quad * 8];
  int sr = tid >> 2;
  int sc = (tid & 3) * 8;
  bf16x8 af[KS];
#pragma unroll
  for (int s = 0; s < KS; s++) af[s] = *(const bf16x8*)&Aptr[s * 32];
#pragma unroll
  for (int it = 0; it < NT; it++) {
    int r = it * 64 + sr;
    *(bf16x8*)&Bs[0][r][sc] = *(const bf16x8*)&Bt[(size_t)r * K + sc];
  }
  __syncthreads();
#pragma unroll
  for (int s = 0; s < KS; s++) {
    int cur = s & 1;
    if (s + 1 < KS) {
#pragma unroll
      for (int it = 0; it < NT; it++) {
        int r = it * 64 + sr;
        *(bf16x8*)&Bs[cur ^ 1][r][sc] = *(const bf16x8*)&Bt[(size_t)r * K + (s + 1) * 32 + sc];
      }
    }
#pragma unroll
    for (int ng = 0; ng < NT * 4; ng++) {
      bf16x8 b = *(const bf16x8*)&Bs[cur][ng * 16 + l16][quad * 8];
      acc[ng] = __builtin_amdgcn_mfma_f32_16x16x32_bf16(af[s], b, acc[ng], 0, 0, 0);
    }
    __syncthreads();
  }
  float asv[NT * 4], adv[NT * 4];
#pragma unroll
  for (int ng = 0; ng < NT * 4; ng++) {
    int c = (ng >> 2) * 64 + (ng & 3) * 16 + l16;
    asv[ng] = a_src[c];
    adv[ng] = a_dst[c];
  }
#pragma unroll
  for (int r = 0; r < 4; r++) {
    int row = rowBase + quad * 4 + r;
#pragma unroll
    for (int h = 0; h < H; h++) {
      float ss = 0.f, sd = 0.f;
#pragma unroll
      for (int g = 0; g < 4; g++) {
        float hv = acc[h * 4 + g][r];
        ss += hv * asv[h * 4 + g];
        sd += hv * adv[h * 4 + g];
      }
#pragma unroll
      for (int o = 1; o < 16; o <<= 1) {
        ss += __shfl_xor(ss, o);
        sd += __shfl_xor(sd, o);
      }
      if (row < M) {
        if (l16 == 0) {
          es[row * H + h] = ss * LOG2E;
          ed[row * H + h] = sd * LOG2E;
        }
        unsigned int pk = 0;
        pk = __builtin_amdgcn_cvt_pk_fp8_f32(acc[h * 4 + 0][r], acc[h * 4 + 1][r], pk, false);
        pk = __builtin_amdgcn_cvt_pk_fp8_f32(acc[h * 4 + 2][r], acc[h * 4 + 3][r], pk, true);
        *(unsigned int*)&C[(size_t)row * Nc + h * 64 + l16 * 4] = pk;
      }
    }
  }
}

// ------- aggregation, HC=256 (layer 0): wave-per-node, register index list, pipelined ------
__global__ void agg256_kernel(const unsigned char* __restrict__ h, const int* __restrict__ offsets,
                              const int* __restrict__ src_sorted, const float* __restrict__ es,
                              const float* __restrict__ ed, const float* __restrict__ bias,
                              __bf16* __restrict__ out, int n) {
  int node = blockIdx.x * (blockDim.x >> 6) + (threadIdx.x >> 6);
  int lane = threadIdx.x & 63;
  if (node >= n) return;
  int quad = lane >> 4;
  int l16 = lane & 15;  // positions l16*16 .. +16
  unsigned hd = (unsigned)(l16 >> 2);
  unsigned cOff = (unsigned)(l16 * 16);
  float myEd = ed[node * 4 + hd];
  int off = offsets[node];
  int deg = offsets[node + 1] - off;
  int idxr = (lane < deg) ? src_sorted[off + lane] : 0;
  float acc[16] = {};
  float sw = 0.f;
  int npre = (deg < 64 ? deg : 64) & ~7;
  int j = 0;
  float eA0 = 0.f, eA1 = 0.f;
  u32x4 uA0 = {}, uA1 = {};
  if (j + 8 <= npre) {
    unsigned sA0 = (unsigned)__shfl(idxr, j + quad);
    unsigned sA1 = (unsigned)__shfl(idxr, j + 4 + quad);
    eA0 = es[sA0 * 4u + hd];
    eA1 = es[sA1 * 4u + hd];
    uA0 = *(const u32x4*)(h + (sA0 << 8) + cOff);
    uA1 = *(const u32x4*)(h + (sA1 << 8) + cOff);
  }
  while (j + 8 <= npre) {
    int jn = j + 8;
    float eB0 = 0.f, eB1 = 0.f;
    u32x4 uB0 = {}, uB1 = {};
    if (jn + 8 <= npre) {
      unsigned sB0 = (unsigned)__shfl(idxr, jn + quad);
      unsigned sB1 = (unsigned)__shfl(idxr, jn + 4 + quad);
      eB0 = es[sB0 * 4u + hd];
      eB1 = es[sB1 * 4u + hd];
      uB0 = *(const u32x4*)(h + (sB0 << 8) + cOff);
      uB1 = *(const u32x4*)(h + (sB1 << 8) + cOff);
    }
    float w0 = fexp2(lrelu(eA0 + myEd));
    float w1 = fexp2(lrelu(eA1 + myEd));
    sw += w0 + w1;
#pragma unroll
    for (int i = 0; i < 4; i++) {
      f32x2 a = __builtin_amdgcn_cvt_pk_f32_fp8(uA0[i], false);
      f32x2 b = __builtin_amdgcn_cvt_pk_f32_fp8(uA0[i], true);
      acc[i * 4 + 0] += w0 * a.x;
      acc[i * 4 + 1] += w0 * a.y;
      acc[i * 4 + 2] += w0 * b.x;
      acc[i * 4 + 3] += w0 * b.y;
    }
#pragma unroll
    for (int i = 0; i < 4; i++) {
      f32x2 a = __builtin_amdgcn_cvt_pk_f32_fp8(uA1[i], false);
      f32x2 b = __builtin_amdgcn_cvt_pk_f32_fp8(uA1[i], true);
      acc[i * 4 + 0] += w1 * a.x;
      acc[i * 4 + 1] += w1 * a.y;
      acc[i * 4 + 2] += w1 * b.x;
      acc[i * 4 + 3] += w1 * b.y;
    }
    eA0 = eB0; eA1 = eB1; uA0 = uB0; uA1 = uB1;
    j = jn;
  }
  for (; j < deg; j += 4) {
    if (quad < deg - j) {
      unsigned s = (unsigned)src_sorted[off + j + quad];
      float w = fexp2(lrelu(es[s * 4u + hd] + myEd));
      sw += w;
      u32x4 u = *(const u32x4*)(h + (s << 8) + cOff);
#pragma unroll
      for (int i = 0; i < 4; i++) {
        f32x2 a = __builtin_amdgcn_cvt_pk_f32_fp8(u[i], false);
        f32x2 b = __builtin_amdgcn_cvt_pk_f32_fp8(u[i], true);
        acc[i * 4 + 0] += w * a.x;
        acc[i * 4 + 1] += w * a.y;
        acc[i * 4 + 2] += w * b.x;
        acc[i * 4 + 3] += w * b.y;
      }
    }
  }
  sw += __shfl_xor(sw, 16);
  sw += __shfl_xor(sw, 32);
#pragma unroll
  for (int k = 0; k < 16; k++) {
    acc[k] += __shfl_xor(acc[k], 16);
    acc[k] += __shfl_xor(acc[k], 32);
  }
  float invS = 1.0f / (sw + 1e-16f);
  if (quad == 0) {
    bf16x8 o0, o1;
#pragma unroll
    for (int k = 0; k < 16; k++) {
      int c = (int)hd * 64 + (k & 3) * 16 + (l16 & 3) * 4 + (k >> 2);  // cmap(l16*16+k)
      float v = fmaxf(acc[k] * invS + bias[c], 0.f);
      if (k < 8) o0[k] = (__bf16)v; else o1[k - 8] = (__bf16)v;
    }
    *(bf16x8*)&out[(size_t)node * 256 + l16 * 16] = o0;
    *(bf16x8*)&out[(size_t)node * 256 + l16 * 16 + 8] = o1;
  }
}

// ------- layer-1 aggregate with FUSED layer-2 projections (wave-per-node) -------
__global__ void agg256f_kernel(const unsigned char* __restrict__ h, const int* __restrict__ offsets,
                               const int* __restrict__ src_sorted, const float* __restrict__ es,
                               const float* __restrict__ ed, const float* __restrict__ bias,
                               const float* __restrict__ wt, const float* __restrict__ vas,
                               const float* __restrict__ vad, f32x2* __restrict__ qes,
                               float* __restrict__ ed2, int n) {
  int node = blockIdx.x * (blockDim.x >> 6) + (threadIdx.x >> 6);
  int lane = threadIdx.x & 63;
  if (node >= n) return;
  int quad = lane >> 4;
  int l16 = lane & 15;
  unsigned hd = (unsigned)(l16 >> 2);
  unsigned cOff = (unsigned)(l16 * 16);
  float myEd = ed[node * 4 + hd];
  int off = offsets[node];
  int deg = offsets[node + 1] - off;
  int idxr = (lane < deg) ? src_sorted[off + lane] : 0;
  float acc[16] = {};
  float sw = 0.f;
  int npre = (deg < 64 ? deg : 64) & ~7;
  int j = 0;
  float eA0 = 0.f, eA1 = 0.f;
  u32x4 uA0 = {}, uA1 = {};
  if (j + 8 <= npre) {
    unsigned sA0 = (unsigned)__shfl(idxr, j + quad);
    unsigned sA1 = (unsigned)__shfl(idxr, j + 4 + quad);
    eA0 = es[sA0 * 4u + hd];
    eA1 = es[sA1 * 4u + hd];
    uA0 = *(const u32x4*)(h + (sA0 << 8) + cOff);
    uA1 = *(const u32x4*)(h + (sA1 << 8) + cOff);
  }
  while (j + 8 <= npre) {
    int jn = j + 8;
    float eB0 = 0.f, eB1 = 0.f;
    u32x4 uB0 = {}, uB1 = {};
    if (jn + 8 <= npre) {
      unsigned sB0 = (unsigned)__shfl(idxr, jn + quad);
      unsigned sB1 = (unsigned)__shfl(idxr, jn + 4 + quad);
      eB0 = es[sB0 * 4u + hd];
      eB1 = es[sB1 * 4u + hd];
      uB0 = *(const u32x4*)(h + (sB0 << 8) + cOff);
      uB1 = *(const u32x4*)(h + (sB1 << 8) + cOff);
    }
    float w0 = fexp2(lrelu(eA0 + myEd));
    float w1 = fexp2(lrelu(eA1 + myEd));
    sw += w0 + w1;
#pragma unroll
    for (int i = 0; i < 4; i++) {
      f32x2 a = __builtin_amdgcn_cvt_pk_f32_fp8(uA0[i], false);
      f32x2 b = __builtin_amdgcn_cvt_pk_f32_fp8(uA0[i], true);
      acc[i * 4 + 0] += w0 * a.x;
      acc[i * 4 + 1] += w0 * a.y;
      acc[i * 4 + 2] += w0 * b.x;
      acc[i * 4 + 3] += w0 * b.y;
    }
#pragma unroll
    for (int i = 0; i < 4; i++) {
      f32x2 a = __builtin_amdgcn_cvt_pk_f32_fp8(uA1[i], false);
      f32x2 b = __builtin_amdgcn_cvt_pk_f32_fp8(uA1[i], true);
      acc[i * 4 + 0] += w1 * a.x;
      acc[i * 4 + 1] += w1 * a.y;
      acc[i * 4 + 2] += w1 * b.x;
      acc[i * 4 + 3] += w1 * b.y;
    }
    eA0 = eB0; eA1 = eB1; uA0 = uB0; uA1 = uB1;
    j = jn;
  }
  for (; j < deg; j += 4) {
    if (quad < deg - j) {
      unsigned s = (unsigned)src_sorted[off + j + quad];
      float w = fexp2(lrelu(es[s * 4u + hd] + myEd));
      sw += w;
      u32x4 u = *(const u32x4*)(h + (s << 8) + cOff);
#pragma unroll
      for (int i = 0; i < 4; i++) {
        f32x2 a = __builtin_amdgcn_cvt_pk_f32_fp8(u[i], false);
        f32x2 b = __builtin_amdgcn_cvt_pk_f32_fp8(u[i], true);
        acc[i * 4 + 0] += w * a.x;
        acc[i * 4 + 1] += w * a.y;
        acc[i * 4 + 2] += w * b.x;
        acc[i * 4 + 3] += w * b.y;
      }
    }
  }
  sw += __shfl_xor(sw, 16);
  sw += __shfl_xor(sw, 32);
#pragma unroll
  for (int k = 0; k < 16; k++) {
    acc[k] += __shfl_xor(acc[k], 16);
    acc[k] += __shfl_xor(acc[k], 32);
  }
  float invS = 1.0f / (sw + 1e-16f);
  // fused layer-2 projections: lane l16 owns 16 true channels; partial dots + 16-lane reduce
  float q = 0.f, s2 = 0.f, d2 = 0.f;
#pragma unroll
  for (int k = 0; k < 16; k++) {
    int c = (int)hd * 64 + (k & 3) * 16 + (l16 & 3) * 4 + (k >> 2);  // cmap(l16*16+k)
    float v = fmaxf(acc[k] * invS + bias[c], 0.f);
    q += v * wt[c];
    s2 += v * vas[c];
    d2 += v * vad[c];
  }
#pragma unroll
  for (int o = 1; o < 16; o <<= 1) {
    q += __shfl_xor(q, o);
    s2 += __shfl_xor(s2, o);
    d2 += __shfl_xor(d2, o);
  }
  if (lane == 0) {
    f32x2 r;
    r.x = q;
    r.y = s2 * LOG2E;  // pre-scaled for exp2
    qes[node] = r;
    ed2[node] = d2 * LOG2E;
  }
}

// ------- layer-2 aggregate + final linear on scalars (400KB L2-resident table).
// One node per 16-lane group (4 nodes/wave) — per-edge body is tiny, divergence negligible. ---
__global__ void agg64v2_kernel(const f32x2* __restrict__ qes, const float* __restrict__ ed2,
                               const int* __restrict__ offsets, const int* __restrict__ src_sorted,
                               const float* __restrict__ bc, float* __restrict__ pnode, int n) {
  int tid = threadIdx.x;
  int node = blockIdx.x * 16 + (tid >> 4);
  if (node >= n) return;
  int g16 = tid & 15;
  float myEd = ed2[node];
  int off = offsets[node];
  int deg = offsets[node + 1] - off;
  float sw = 0.f, swq = 0.f;
  for (int j = g16; j < deg; j += 16) {
    int s = src_sorted[off + j];
    f32x2 v = qes[s];
    float w = fexp2(lrelu(v.y + myEd));
    sw += w;
    swq += w * v.x;
  }
#pragma unroll
  for (int o = 1; o < 16; o <<= 1) {
    sw += __shfl_xor(sw, o);
    swq += __shfl_xor(swq, o);
  }
  if (g16 == 0) pnode[node] = swq / (sw + 1e-16f) + bc[0];
}

// ---------------- FUSED pool+final: block g binary-searches its segment, reduces, writes out ----
static __device__ __forceinline__ int lowerb(const int* __restrict__ a, int n, int key) {
  int lo = 0, hi = n;
  while (lo < hi) {
    int mid = (lo + hi) >> 1;
    if (a[mid] < key) lo = mid + 1; else hi = mid;
  }
  return lo;
}

__global__ void poolfinal_kernel(const float* __restrict__ pnode, const int* __restrict__ batch,
                                 const float* __restrict__ lin_b, float* __restrict__ out, int n) {
  __shared__ float ws[4];
  int g = blockIdx.x;
  int start = lowerb(batch, n, g);
  int end = lowerb(batch, n, g + 1);
  float acc = 0.f;
  for (int i = start + threadIdx.x; i < end; i += 256) acc += pnode[i];
  for (int o = 32; o > 0; o >>= 1) acc += __shfl_down(acc, o);
  if ((threadIdx.x & 63) == 0) ws[threadIdx.x >> 6] = acc;
  __syncthreads();
  if (threadIdx.x == 0) {
    float total = ws[0] + ws[1] + ws[2] + ws[3];
    out[g] = total / fmaxf((float)(end - start), 1.0f) + lin_b[0];
  }
}

extern "C" void kernel_launch(void* const* d_in, const int* in_sizes, int n_in, void* d_out,
                              int out_size, void* d_ws, size_t ws_size, hipStream_t stream) {
  const float* x = (const float*)d_in[0];
  const int* edge_index = (const int*)d_in[1];
  const int* batch = (const int*)d_in[2];
  const float* W0 = (const float*)d_in[3];
  const float* a_src0 = (const float*)d_in[4];
  const float* a_dst0 = (const float*)d_in[5];
  const float* b0 = (const float*)d_in[6];
  const float* W1 = (const float*)d_in[7];
  const float* a_src1 = (const float*)d_in[8];
  const float* a_dst1 = (const float*)d_in[9];
  const float* b1 = (const float*)d_in[10];
  const float* W2 = (const float*)d_in[11];
  const float* a_src2 = (const float*)d_in[12];
  const float* a_dst2 = (const float*)d_in[13];
  const float* b2 = (const float*)d_in[14];
  const float* lin_w = (const float*)d_in[15];
  const float* lin_b = (const float*)d_in[16];
  float* out = (float*)d_out;

  const int N = in_sizes[2];      // 50000
  const int E = in_sizes[1] / 2;  // 800000
  const int EE = E + N;
  const int G = 64;
  const int FIN = in_sizes[0] / N;  // 128

  const int* srcArr = edge_index;
  const int* dstArr = edge_index + E;

  // workspace carve (256B aligned)
  size_t off = 0;
  auto alloc = [&](size_t bytes) -> void* {
    off = (off + 255) & ~(size_t)255;
    void* p = (char*)d_ws + off;
    off += bytes;
    return p;
  };
  unsigned char* hA = (unsigned char*)alloc((size_t)N * 256);  // GEMM out, fp8 permuted
  __bf16* hB = (__bf16*)alloc((size_t)N * 256 * 2);            // layer-0 aggregate out, bf16
  float* pnode = (float*)alloc((size_t)N * 4);
  __bf16* Bt0 = (__bf16*)alloc((size_t)256 * FIN * 2);
  __bf16* Bt1 = (__bf16*)alloc((size_t)256 * 256 * 2);
  float* es = (float*)alloc((size_t)N * 4 * 4);
  float* ed = (float*)alloc((size_t)N * 4 * 4);
  int* offsets = (int*)alloc((size_t)(N + 1) * 4);
  int* src_sorted = (int*)alloc((size_t)EE * 4);
  int* bucket_cnt = (int*)alloc((size_t)4096 * 4);  // 196 buckets padded to 64B stride
  f32x2* qes = (f32x2*)alloc((size_t)N * 8);        // {q_j, es2_j} packed for one 8B gather
  float* ed2 = (float*)alloc((size_t)N * 4);
  float* wt = (float*)alloc(256 * 4);
  float* vas = (float*)alloc(256 * 4);
  float* vad = (float*)alloc(256 * 4);
  float* bc = (float*)alloc(256);  // 1 float, padded
  (void)ws_size;

  int NB = (N + 255) >> 8;  // dst-range buckets (256 nodes each)

  // part[] lives only between gemm_part and bucket_csr; hB is first written later by
  // agg256 -> alias part onto hB (NB*BCAP*4 = 6.4MB << 25.6MB).
  unsigned int* part = (unsigned int*)hB;

  int nwb = (N + 3) / 4;        // agg256*: one node per wave, 4 waves/block
  int ngb = (N + 15) / 16;      // agg64v2: one node per 16-lane group
  int gmx = (N + 63) / 64;      // GEMM M-blocks (64 rows each)
  int nA = (EE + 4095) / 4096;  // partition blocks (4096 edges each)

  // ---- prep (weight transposes + layer-2 composite vectors + zero bucket counters) ----
  prep_kernel<<<256 + 256 + 1 + 16, 256, 0, stream>>>(W0, Bt0, W1, Bt1, FIN, W2, lin_w, a_src2,
                                                      a_dst2, b2, wt, vas, vad, bc, bucket_cnt,
                                                      4096);

  // ---- layer-0 GEMM (reads f32 x directly, cvt in-register) + edge bucket-partition ----
  gemm_part_kernel<128, 4><<<gmx + nA, 256, 0, stream>>>(
      x, Bt0, a_src0, a_dst0, hA, es, ed, N, gmx, srcArr, dstArr, bucket_cnt, part, E, EE, N);

  // ---- per-bucket CSR finalize ----
  bucket_csr_kernel<<<NB, 1024, 0, stream>>>(part, bucket_cnt, offsets, src_sorted, N, EE);

  // ---- layer 0 aggregate (wave-per-node) ----
  agg256_kernel<<<nwb, 256, 0, stream>>>(hA, offsets, src_sorted, es, ed, b0, hB, N);

  // ---- layer 1: 256 -> 4x64 concat, relu ----
  gemm2_kernel<256, 4><<<gmx, 256, 0, stream>>>(hB, Bt1, a_src1, a_dst1, hA, es, ed, N);

  // ---- layer-1 aggregate with fused layer-2 projections (wave-per-node) ----
  agg256f_kernel<<<nwb, 256, 0, stream>>>(hA, offsets, src_sorted, es, ed, b1, wt, vas, vad, qes,
                                          ed2, N);

  // ---- layer-2 aggregate + final linear on scalars (group-per-node, L2-resident table) ----
  agg64v2_kernel<<<ngb, 256, 0, stream>>>(qes, ed2, offsets, src_sorted, bc, pnode, N);

  // ---- fused global mean pool + bias (binary-search segments) ----
  poolfinal_kernel<<<G, 256, 0, stream>>>(pnode, batch, lin_b, out, N);
}